// Round 9
// baseline (240.122 us; speedup 1.0000x reference)
//
#include <hip/hip_runtime.h>

// FBSNN loss — bf16 MFMA, permuted-k layout (no cross-lane exchange).
// Round 9 = round 8 with VOLATILE asm laundering in phase 1. Non-volatile asm
// (r7/r8) was legally sunk back into the loop together with its ds_read,
// defeating register residency (VGPR_Count stayed 132 < 144-frag minimum).
// Volatile asm is pinned: executes once before the 50-step serial loop.
//
// Phase 1: sequential q-net scan. 128 blocks x 64 thr (1 wave = 32 paths).
// Phase 2: Y-net + tangent at 51*4096 points, 408 blocks x 4 waves x 4 tiles.
// Phase 3: residuals + reduction, parallel over paths and step-chunks.

#define NPATH   4096
#define NSTEP   50
#define DT_F    0.02f
#define SQRT_DT 0.14142136f
#define SIGMA_F 0.5f

typedef __attribute__((ext_vector_type(8)))  short s16x8;
typedef __attribute__((ext_vector_type(16))) float f32x16;

__device__ __forceinline__ unsigned pkbf(float a, float b) {
    unsigned ua = __float_as_uint(a), ub = __float_as_uint(b);
    ua += 0x7fffu + ((ua >> 16) & 1u);
    ub += 0x7fffu + ((ub >> 16) & 1u);
    return (ua >> 16) | (ub & 0xffff0000u);
}

__device__ __forceinline__ s16x8 frag4(unsigned a, unsigned b, unsigned c, unsigned d) {
    union { unsigned u[4]; s16x8 s; } x;
    x.u[0] = a; x.u[1] = b; x.u[2] = c; x.u[3] = d;
    return x.s;
}

__device__ __forceinline__ s16x8 frag_of(uint4 v) {
    union { uint4 q; s16x8 s; } x; x.q = v; return x.s;
}

// VOLATILE opaque def: cannot be hoisted/sunk/duplicated/deleted -> the
// laundered values must stay live in VGPRs across the whole loop.
__device__ __forceinline__ s16x8 launder_frag(uint4 v) {
    unsigned a = v.x, b = v.y, c = v.z, d = v.w;
    asm volatile("" : "+v"(a), "+v"(b), "+v"(c), "+v"(d));
    return frag4(a, b, c, d);
}

__device__ __forceinline__ f32x16 zf() {
    f32x16 v;
#pragma unroll
    for (int i = 0; i < 16; ++i) v[i] = 0.0f;
    return v;
}

// ---- frag table builder, PERMUTED k (swap bits 2<->3 of k) ----
// e=0..1: input (tau=e); e=2..31: hidden (2+L*10+tau*5+b, b=4 is bias);
// e=32..35: Wout k-blocks. Hidden/out element (h,b,i) holds input-unit
// u_in = 16b + 4h + (i&3) + 8*(i>>2).
__device__ __forceinline__ void build_frags(
    const float* __restrict__ Win, const float* __restrict__ bin,
    const float* __restrict__ Whid, const float* __restrict__ bhid,
    const float* __restrict__ Wout,
    uint4* __restrict__ fragLDS, int l, int h, int m, int e0, int estep)
{
    for (int e = e0; e < 36; e += estep) {
        unsigned w0 = 0, w1 = 0, w2 = 0, w3 = 0;
        if (e < 2) {                     // input layer: k0=t, k1=y, k2=bias (no perm)
            int u = 32 * e + m;
            if (h == 0) {
                w0 = pkbf(Win[u], Win[64 + u]);
                w1 = pkbf(bin[u], 0.0f);
            }
        } else if (e < 32) {
            int e2 = e - 2;
            int L = e2 / 10, rem = e2 % 10;
            int tau = rem / 5, b = rem % 5;
            int u = 32 * tau + m;
            if (b < 4) {
                int k0 = 16 * b + 4 * h;
                const float* Wp = Whid + L * 4096 + u;
                w0 = pkbf(Wp[(k0 + 0)  * 64], Wp[(k0 + 1)  * 64]);
                w1 = pkbf(Wp[(k0 + 2)  * 64], Wp[(k0 + 3)  * 64]);
                w2 = pkbf(Wp[(k0 + 8)  * 64], Wp[(k0 + 9)  * 64]);
                w3 = pkbf(Wp[(k0 + 10) * 64], Wp[(k0 + 11) * 64]);
            } else {
                if (h == 0) w0 = pkbf(bhid[L * 64 + u], 0.0f);   // bias at k=0
            }
        } else {
            int b = e - 32;
            if (m == 0) {
                int k0 = 16 * b + 4 * h;
                w0 = pkbf(Wout[k0 + 0],  Wout[k0 + 1]);
                w1 = pkbf(Wout[k0 + 2],  Wout[k0 + 3]);
                w2 = pkbf(Wout[k0 + 8],  Wout[k0 + 9]);
                w3 = pkbf(Wout[k0 + 10], Wout[k0 + 11]);
            }
        }
        fragLDS[e * 64 + l] = make_uint4(w0, w1, w2, w3);
    }
}

// fwd-only transition, no cross-lane ops: Bf from own C regs
__device__ __forceinline__ void trans_fwd(const f32x16& C0, const f32x16& C1,
                                          s16x8* Bf)
{
    float a0[16], a1[16];
#pragma unroll
    for (int r = 0; r < 16; ++r) { a0[r] = __sinf(C0[r]); a1[r] = __sinf(C1[r]); }
#pragma unroll
    for (int b = 0; b < 4; ++b) {
        const float* A = (b & 2) ? a1 : a0;
        unsigned w[4];
#pragma unroll
        for (int j = 0; j < 4; ++j) {
            const int rb = 2 * (j & 1) + 4 * (j >> 1) + 8 * (b & 1);
            w[j] = pkbf(A[rb], A[rb + 1]);
        }
        Bf[b] = frag4(w[0], w[1], w[2], w[3]);
    }
}

// fwd+tangent transition, no cross-lane ops
__device__ __forceinline__ void trans_tan(
    const f32x16& Cf0, const f32x16& Cf1, const f32x16& Ct0, const f32x16& Ct1,
    s16x8* Bf, s16x8* Bt)
{
    float sf0[16], sf1[16], st0[16], st1[16];
#pragma unroll
    for (int r = 0; r < 16; ++r) {
        float s, c;
        __sincosf(Cf0[r], &s, &c); sf0[r] = s; st0[r] = c * Ct0[r];
    }
#pragma unroll
    for (int r = 0; r < 16; ++r) {
        float s, c;
        __sincosf(Cf1[r], &s, &c); sf1[r] = s; st1[r] = c * Ct1[r];
    }
#pragma unroll
    for (int b = 0; b < 4; ++b) {
        const float* F = (b & 2) ? sf1 : sf0;
        const float* T = (b & 2) ? st1 : st0;
        unsigned wf[4], wt[4];
#pragma unroll
        for (int j = 0; j < 4; ++j) {
            const int rb = 2 * (j & 1) + 4 * (j >> 1) + 8 * (b & 1);
            wf[j] = pkbf(F[rb], F[rb + 1]);
            wt[j] = pkbf(T[rb], T[rb + 1]);
        }
        Bf[b] = frag4(wf[0], wf[1], wf[2], wf[3]);
        Bt[b] = frag4(wt[0], wt[1], wt[2], wt[3]);
    }
}

// ================= Phase 1: q-net scan =================

extern "C" __global__ void __launch_bounds__(64, 1)
fbsnn_phase1(const float* __restrict__ q_Win, const float* __restrict__ q_bin,
             const float* __restrict__ q_Whid, const float* __restrict__ q_bhid,
             const float* __restrict__ q_Wout, const float* __restrict__ q_bout,
             const float* __restrict__ y0p, const float* __restrict__ dW,
             float* __restrict__ y_ws, float* __restrict__ q_ws)
{
    __shared__ uint4 fragLDS[36 * 64];

    const int l = (int)(threadIdx.x & 63);
    const int h = l >> 5;
    const int m = l & 31;
    const int p = (int)blockIdx.x * 32 + m;

    build_frags(q_Win, q_bin, q_Whid, q_bhid, q_Wout, fragLDS, l, h, m, 0, 1);
    __syncthreads();

    // hoist + VOLATILE launder: 144 VGPRs of frags forced live across the loop
    s16x8 F[36];
#pragma unroll
    for (int e = 0; e < 36; ++e) F[e] = launder_frag(fragLDS[e * 64 + l]);

    const float qb = q_bout[0];
    const s16x8 Bone = frag4(h ? 0u : pkbf(1.0f, 0.0f), 0u, 0u, 0u);

    float y = y0p[0];
    float dw_cur = dW[p];

    for (int n = 0; n < NSTEP; ++n) {
        const float t = n * DT_F;
        if (h == 0) y_ws[n * NPATH + p] = y;

        const int n1 = (n + 1 < NSTEP) ? n + 1 : NSTEP - 1;
        const float dw_next = dW[n1 * NPATH + p];

        const s16x8 Bty = frag4(h ? 0u : pkbf(t, y), h ? 0u : pkbf(1.0f, 0.0f), 0u, 0u);

        // input layer
        f32x16 C0 = zf(), C1 = zf();
        C0 = __builtin_amdgcn_mfma_f32_32x32x16_bf16(F[0], Bty, C0, 0, 0, 0);
        C1 = __builtin_amdgcn_mfma_f32_32x32x16_bf16(F[1], Bty, C1, 0, 0, 0);
        s16x8 Bf[4];
        trans_fwd(C0, C1, Bf);

        // hidden layers: bias-seeded single accumulator per tile
#pragma unroll
        for (int L = 0; L < 3; ++L) {
            const int base = 2 + L * 10;
            C0 = zf(); C1 = zf();
            C0 = __builtin_amdgcn_mfma_f32_32x32x16_bf16(F[base + 4], Bone, C0, 0, 0, 0);
            C1 = __builtin_amdgcn_mfma_f32_32x32x16_bf16(F[base + 9], Bone, C1, 0, 0, 0);
#pragma unroll
            for (int b = 0; b < 4; ++b) {
                C0 = __builtin_amdgcn_mfma_f32_32x32x16_bf16(F[base + b],     Bf[b], C0, 0, 0, 0);
                C1 = __builtin_amdgcn_mfma_f32_32x32x16_bf16(F[base + 5 + b], Bf[b], C1, 0, 0, 0);
            }
            trans_fwd(C0, C1, Bf);
        }

        // output layer
        f32x16 Co = zf();
#pragma unroll
        for (int b = 0; b < 4; ++b)
            Co = __builtin_amdgcn_mfma_f32_32x32x16_bf16(F[32 + b], Bf[b], Co, 0, 0, 0);

        const float q = Co[0] + qb;                  // valid at h==0, col=m
        if (h == 0) q_ws[n * NPATH + p] = q;
        y = fmaf(q, DT_F, y) + SIGMA_F * (dw_cur * SQRT_DT);
        dw_cur = dw_next;
    }
    if (h == 0) y_ws[NSTEP * NPATH + p] = y;
}

// ================= Phase 2: Y-net + tangent =================

#define NTILES 1632          // 208896 points / 128 per block
#define P2GRID 408           // 4 tiles per block exactly

extern "C" __global__ void __launch_bounds__(256, 2)
fbsnn_phase2(const float* __restrict__ Y_Win, const float* __restrict__ Y_bin,
             const float* __restrict__ Y_Whid, const float* __restrict__ Y_bhid,
             const float* __restrict__ Y_Wout, const float* __restrict__ Y_bout,
             const float* __restrict__ y_ws, float* __restrict__ Y_ws,
             float* __restrict__ dY_ws)
{
    __shared__ uint4 fragLDS[36 * 64];

    const int tid = (int)threadIdx.x;
    const int wv  = tid >> 6;
    const int l   = tid & 63;
    const int h   = l >> 5;
    const int m   = l & 31;

    build_frags(Y_Win, Y_bin, Y_Whid, Y_bhid, Y_Wout, fragLDS, l, h, m, wv, 4);
    __syncthreads();

    const float bout = Y_bout[0];
    const s16x8 Btn  = frag4(h ? 0u : pkbf(0.0f, 1.0f), 0u, 0u, 0u);
    const s16x8 Bone = frag4(h ? 0u : pkbf(1.0f, 0.0f), 0u, 0u, 0u);

    for (int tile = (int)blockIdx.x; tile < NTILES; tile += P2GRID) {
        const int point = tile * 128 + wv * 32 + m;
        const int n = point >> 12;
        const float t = n * DT_F;
        const float y = y_ws[point];

        const s16x8 Bty = frag4(h ? 0u : pkbf(t, y), h ? 0u : pkbf(1.0f, 0.0f), 0u, 0u);

        f32x16 Cf0 = zf(), Cf1 = zf(), Ct0 = zf(), Ct1 = zf();
        {
            s16x8 A0 = frag_of(fragLDS[0 * 64 + l]);
            s16x8 A1 = frag_of(fragLDS[1 * 64 + l]);
            Cf0 = __builtin_amdgcn_mfma_f32_32x32x16_bf16(A0, Bty, Cf0, 0, 0, 0);
            Cf1 = __builtin_amdgcn_mfma_f32_32x32x16_bf16(A1, Bty, Cf1, 0, 0, 0);
            Ct0 = __builtin_amdgcn_mfma_f32_32x32x16_bf16(A0, Btn, Ct0, 0, 0, 0);
            Ct1 = __builtin_amdgcn_mfma_f32_32x32x16_bf16(A1, Btn, Ct1, 0, 0, 0);
        }
        s16x8 Bf[4], Bt[4];
        trans_tan(Cf0, Cf1, Ct0, Ct1, Bf, Bt);

#pragma unroll
        for (int L = 0; L < 3; ++L) {
            const int base = 2 + L * 10;
            Cf0 = zf(); Cf1 = zf(); Ct0 = zf(); Ct1 = zf();
            Cf0 = __builtin_amdgcn_mfma_f32_32x32x16_bf16(frag_of(fragLDS[(base + 4) * 64 + l]), Bone, Cf0, 0, 0, 0);
            Cf1 = __builtin_amdgcn_mfma_f32_32x32x16_bf16(frag_of(fragLDS[(base + 9) * 64 + l]), Bone, Cf1, 0, 0, 0);
#pragma unroll
            for (int b = 0; b < 4; ++b) {
                s16x8 A0 = frag_of(fragLDS[(base + 0 + b) * 64 + l]);
                s16x8 A1 = frag_of(fragLDS[(base + 5 + b) * 64 + l]);
                Cf0 = __builtin_amdgcn_mfma_f32_32x32x16_bf16(A0, Bf[b], Cf0, 0, 0, 0);
                Ct0 = __builtin_amdgcn_mfma_f32_32x32x16_bf16(A0, Bt[b], Ct0, 0, 0, 0);
                Cf1 = __builtin_amdgcn_mfma_f32_32x32x16_bf16(A1, Bf[b], Cf1, 0, 0, 0);
                Ct1 = __builtin_amdgcn_mfma_f32_32x32x16_bf16(A1, Bt[b], Ct1, 0, 0, 0);
            }
            trans_tan(Cf0, Cf1, Ct0, Ct1, Bf, Bt);
        }

        f32x16 Cof = zf(), Cot = zf();
#pragma unroll
        for (int b = 0; b < 4; ++b) {
            s16x8 Ao = frag_of(fragLDS[(32 + b) * 64 + l]);
            Cof = __builtin_amdgcn_mfma_f32_32x32x16_bf16(Ao, Bf[b], Cof, 0, 0, 0);
            Cot = __builtin_amdgcn_mfma_f32_32x32x16_bf16(Ao, Bt[b], Cot, 0, 0, 0);
        }
        if (h == 0) {
            Y_ws[point]  = Cof[0] + bout;
            dY_ws[point] = Cot[0];
        }
    }
}

// ================= Phase 3: residuals + reduction =================
// grid.x: path blocks (16), grid.y: step chunks of 10 (5)

extern "C" __global__ void __launch_bounds__(256)
fbsnn_phase3(const float* __restrict__ y_ws, const float* __restrict__ q_ws,
             const float* __restrict__ Y_ws, const float* __restrict__ dY_ws,
             const float* __restrict__ dW, float* __restrict__ out)
{
    const int p  = blockIdx.x * 256 + threadIdx.x;
    const int n0 = blockIdx.y * 10;

    float acc = 0.0f;
    float Yc  = Y_ws[n0 * NPATH + p];
#pragma unroll
    for (int k = 0; k < 10; ++k) {
        const int n = n0 + k;
        float q    = q_ws[n * NPATH + p];
        float dYc  = dY_ws[n * NPATH + p];
        float dws  = dW[n * NPATH + p] * SQRT_DT;
        float Yn   = Y_ws[(n + 1) * NPATH + p];
        float Ytil = fmaf(-q * q, DT_F, Yc) + (SIGMA_F * dYc) * dws;
        float r    = Yn - Ytil;
        acc = fmaf(r, r, acc);
        Yc = Yn;
    }
    if (blockIdx.y == 4) {
        float y50  = y_ws[NSTEP * NPATH + p];
        float dY50 = dY_ws[NSTEP * NPATH + p];
        float r1 = Yc - y50 * y50;
        float r2 = dY50 - 2.0f * y50;
        acc = fmaf(r1, r1, fmaf(r2, r2, acc));
    }

    float v = acc;
#pragma unroll
    for (int off = 32; off > 0; off >>= 1) v += __shfl_down(v, off, 64);
    if ((threadIdx.x & 63) == 0) atomicAdd(out, v * (1.0f / (float)NPATH));
}

// ================= host launch =================

extern "C" void kernel_launch(void* const* d_in, const int* in_sizes, int n_in,
                              void* d_out, int out_size, void* d_ws, size_t ws_size,
                              hipStream_t stream)
{
    const float* Y_Win  = (const float*)d_in[0];
    const float* Y_bin  = (const float*)d_in[1];
    const float* Y_Whid = (const float*)d_in[2];
    const float* Y_bhid = (const float*)d_in[3];
    const float* Y_Wout = (const float*)d_in[4];
    const float* Y_bout = (const float*)d_in[5];
    const float* q_Win  = (const float*)d_in[6];
    const float* q_bin  = (const float*)d_in[7];
    const float* q_Whid = (const float*)d_in[8];
    const float* q_bhid = (const float*)d_in[9];
    const float* q_Wout = (const float*)d_in[10];
    const float* q_bout = (const float*)d_in[11];
    const float* y0p    = (const float*)d_in[12];
    const float* dW     = (const float*)d_in[13];

    float* ws    = (float*)d_ws;
    float* y_ws  = ws;                          // 51*4096
    float* q_ws  = ws + 51 * NPATH;             // 50*4096
    float* Y_ws  = ws + 101 * NPATH;            // 51*4096
    float* dY_ws = ws + 152 * NPATH;            // 51*4096

    hipMemsetAsync(d_out, 0, sizeof(float), stream);

    fbsnn_phase1<<<dim3(128), dim3(64), 0, stream>>>(
        q_Win, q_bin, q_Whid, q_bhid, q_Wout, q_bout, y0p, dW, y_ws, q_ws);

    fbsnn_phase2<<<dim3(P2GRID), dim3(256), 0, stream>>>(
        Y_Win, Y_bin, Y_Whid, Y_bhid, Y_Wout, Y_bout, y_ws, Y_ws, dY_ws);

    fbsnn_phase3<<<dim3(NPATH / 256, 5), dim3(256), 0, stream>>>(
        y_ws, q_ws, Y_ws, dY_ws, dW, (float*)d_out);
}

// Round 10
// 181.412 us; speedup vs baseline: 1.3236x; 1.3236x over previous
//
#include <hip/hip_runtime.h>

// FBSNN loss — bf16 MFMA.
// Round 10: phase 1 rewritten on 16x16x32 MFMA with a zero-shuffle unit
// permutation u = 8*qd + 4t + i (t<2; +32 for t>=2): each lane's 4 C/D tiles
// ARE its two next-layer B-frags in register order. Chain/layer = 2 dependent
// MFMAs + 16 sins; bias via C-init (no seed MFMA); weights prescaled by 1/2pi
// so v_sin consumes the accumulator directly. 256 blocks x 1 wave = 16 paths
// per wave, all 256 CUs.
// Phase 2 (32x32 points-as-N, permuted-k) and phase 3 unchanged from round 9.

#define NPATH   4096
#define NSTEP   50
#define DT_F    0.02f
#define SQRT_DT 0.14142136f
#define SIGMA_F 0.5f
#define INV2PI  0.15915494309189535f

typedef __attribute__((ext_vector_type(8)))  short s16x8;
typedef __attribute__((ext_vector_type(4)))  float f32x4;
typedef __attribute__((ext_vector_type(16))) float f32x16;

__device__ __forceinline__ unsigned pkbf(float a, float b) {
    unsigned ua = __float_as_uint(a), ub = __float_as_uint(b);
    ua += 0x7fffu + ((ua >> 16) & 1u);
    ub += 0x7fffu + ((ub >> 16) & 1u);
    return (ua >> 16) | (ub & 0xffff0000u);
}

__device__ __forceinline__ s16x8 frag4(unsigned a, unsigned b, unsigned c, unsigned d) {
    union { unsigned u[4]; s16x8 s; } x;
    x.u[0] = a; x.u[1] = b; x.u[2] = c; x.u[3] = d;
    return x.s;
}

__device__ __forceinline__ s16x8 frag_of(uint4 v) {
    union { uint4 q; s16x8 s; } x; x.q = v; return x.s;
}

__device__ __forceinline__ f32x16 zf() {
    f32x16 v;
#pragma unroll
    for (int i = 0; i < 16; ++i) v[i] = 0.0f;
    return v;
}

// sin of (x revolutions)
__device__ __forceinline__ float sinrev(float x) {
#if __has_builtin(__builtin_amdgcn_sinf)
    return __builtin_amdgcn_sinf(x);
#else
    return __sinf(x * 6.28318530717958647f);
#endif
}

// ================= Phase 1: q-net scan on 16x16x32 =================
// Unit slot mapping: output unit produced at (tile t, C/D-row r):
//   u = 8*(r>>2) + 4*t + (r&3)           for t in {0,1}
//   u = 32 + 8*(r>>2) + 4*(t-2) + (r&3)  for t in {2,3}
// Consumer side needs NO permutation: B k-position k holds unit k (frag0) or
// 32+k (frag1), because k = 8*qd + j and u = 8*qd + 4t + i with j = 4t+i.

__device__ __forceinline__ int slot16(int t, int r) {
    return (t < 2) ? 8 * (r >> 2) + 4 * t + (r & 3)
                   : 32 + 8 * (r >> 2) + 4 * (t - 2) + (r & 3);
}

// transition: 4 C tiles -> 2 B-frags (pure sin + sequential pack)
__device__ __forceinline__ void trans16(const f32x4* C, s16x8& B0, s16x8& B1) {
    float a[4][4];
#pragma unroll
    for (int t = 0; t < 4; ++t)
#pragma unroll
        for (int i = 0; i < 4; ++i) a[t][i] = sinrev(C[t][i]);
    B0 = frag4(pkbf(a[0][0], a[0][1]), pkbf(a[0][2], a[0][3]),
               pkbf(a[1][0], a[1][1]), pkbf(a[1][2], a[1][3]));
    B1 = frag4(pkbf(a[2][0], a[2][1]), pkbf(a[2][2], a[2][3]),
               pkbf(a[3][0], a[3][1]), pkbf(a[3][2], a[3][3]));
}

extern "C" __global__ void __launch_bounds__(64, 1)
fbsnn_phase1(const float* __restrict__ q_Win, const float* __restrict__ q_bin,
             const float* __restrict__ q_Whid, const float* __restrict__ q_bhid,
             const float* __restrict__ q_Wout, const float* __restrict__ q_bout,
             const float* __restrict__ y0p, const float* __restrict__ dW,
             float* __restrict__ y_ws, float* __restrict__ q_ws)
{
    const int l  = (int)(threadIdx.x & 63);
    const int qd = l >> 4;
    const int m  = l & 15;
    const int p  = (int)blockIdx.x * 16 + m;     // path (lanes qd==0 own state)

    // ---- build register-resident frags by per-lane global gathers ----
    int uoA[4], uoB[4];                          // A rows use m; bias rows use 4qd+i base
#pragma unroll
    for (int t = 0; t < 4; ++t) uoA[t] = slot16(t, m);

    // input layer: A[m][k]: k=0 -> t-coeff, k=1 -> y-coeff (lanes qd==0 only)
    s16x8 Ain[4];
#pragma unroll
    for (int t = 0; t < 4; ++t) {
        unsigned w0 = 0;
        if (qd == 0)
            w0 = pkbf(INV2PI * q_Win[uoA[t]], INV2PI * q_Win[64 + uoA[t]]);
        Ain[t] = frag4(w0, 0u, 0u, 0u);
    }

    // hidden layers: A[m][k] = S * Whid[u_in][u_out], u_in = 32*kk + 8*qd + j
    s16x8 AH[3][4][2];
#pragma unroll
    for (int L = 0; L < 3; ++L)
#pragma unroll
        for (int t = 0; t < 4; ++t)
#pragma unroll
            for (int kk = 0; kk < 2; ++kk) {
                const float* W = q_Whid + L * 4096 + uoA[t];
                unsigned w[4];
#pragma unroll
                for (int j2 = 0; j2 < 4; ++j2) {
                    int e0 = 32 * kk + 8 * qd + 2 * j2;
                    w[j2] = pkbf(INV2PI * W[e0 * 64], INV2PI * W[(e0 + 1) * 64]);
                }
                AH[L][t][kk] = frag4(w[0], w[1], w[2], w[3]);
            }

    // output layer: A row 0 only (lanes m==0), unscaled
    s16x8 Aout[2];
#pragma unroll
    for (int kk = 0; kk < 2; ++kk) {
        unsigned w[4] = {0u, 0u, 0u, 0u};
        if (m == 0) {
#pragma unroll
            for (int j2 = 0; j2 < 4; ++j2) {
                int e0 = 32 * kk + 8 * qd + 2 * j2;
                w[j2] = pkbf(q_Wout[e0], q_Wout[e0 + 1]);
            }
        }
        Aout[kk] = frag4(w[0], w[1], w[2], w[3]);
    }

    // biases (prescaled), indexed by C/D row r = 4*qd + i
    float bIn[4][4], bHd[3][4][4];
#pragma unroll
    for (int t = 0; t < 4; ++t) {
#pragma unroll
        for (int i = 0; i < 4; ++i) {
            int u = slot16(t, 4 * qd + i);
            bIn[t][i] = INV2PI * q_bin[u];
#pragma unroll
            for (int L = 0; L < 3; ++L)
                bHd[L][t][i] = INV2PI * q_bhid[L * 64 + u];
        }
        uoB[t] = 0; (void)uoB;
    }
    const float qb = q_bout[0];

    float y = y0p[0];
    float dw_cur = (qd == 0) ? dW[p] : 0.0f;

    for (int n = 0; n < NSTEP; ++n) {
        const float tt = n * DT_F;
        if (qd == 0) y_ws[n * NPATH + p] = y;

        const int n1 = (n + 1 < NSTEP) ? n + 1 : NSTEP - 1;
        const float dw_next = (qd == 0) ? dW[n1 * NPATH + p] : 0.0f;

        const s16x8 Bty = frag4((qd == 0) ? pkbf(tt, y) : 0u, 0u, 0u, 0u);

        // ---- input layer: C-init = bias, one MFMA per tile (independent) ----
        f32x4 C[4];
#pragma unroll
        for (int t = 0; t < 4; ++t) {
            f32x4 c; c[0] = bIn[t][0]; c[1] = bIn[t][1]; c[2] = bIn[t][2]; c[3] = bIn[t][3];
            C[t] = __builtin_amdgcn_mfma_f32_16x16x32_bf16(Ain[t], Bty, c, 0, 0, 0);
        }
        s16x8 B0, B1;
        trans16(C, B0, B1);

        // ---- hidden layers: C-init = bias, 2 dependent MFMAs per tile ----
#pragma unroll
        for (int L = 0; L < 3; ++L) {
#pragma unroll
            for (int t = 0; t < 4; ++t) {
                f32x4 c; c[0] = bHd[L][t][0]; c[1] = bHd[L][t][1];
                c[2] = bHd[L][t][2]; c[3] = bHd[L][t][3];
                c = __builtin_amdgcn_mfma_f32_16x16x32_bf16(AH[L][t][0], B0, c, 0, 0, 0);
                C[t] = __builtin_amdgcn_mfma_f32_16x16x32_bf16(AH[L][t][1], B1, c, 0, 0, 0);
            }
            trans16(C, B0, B1);
        }

        // ---- output layer ----
        f32x4 Co; Co[0] = 0.0f; Co[1] = 0.0f; Co[2] = 0.0f; Co[3] = 0.0f;
        Co = __builtin_amdgcn_mfma_f32_16x16x32_bf16(Aout[0], B0, Co, 0, 0, 0);
        Co = __builtin_amdgcn_mfma_f32_16x16x32_bf16(Aout[1], B1, Co, 0, 0, 0);

        const float q = Co[0] + qb;              // row0 col=m: valid at qd==0
        if (qd == 0) q_ws[n * NPATH + p] = q;
        y = fmaf(q, DT_F, y) + SIGMA_F * (dw_cur * SQRT_DT);
        dw_cur = dw_next;
    }
    if (qd == 0) y_ws[NSTEP * NPATH + p] = y;
}

// ================= Phase 2: Y-net + tangent (round-9, 32x32 permuted-k) ======

__device__ __forceinline__ void build_frags(
    const float* __restrict__ Win, const float* __restrict__ bin,
    const float* __restrict__ Whid, const float* __restrict__ bhid,
    const float* __restrict__ Wout,
    uint4* __restrict__ fragLDS, int l, int h, int m, int e0, int estep)
{
    for (int e = e0; e < 36; e += estep) {
        unsigned w0 = 0, w1 = 0, w2 = 0, w3 = 0;
        if (e < 2) {
            int u = 32 * e + m;
            if (h == 0) {
                w0 = pkbf(Win[u], Win[64 + u]);
                w1 = pkbf(bin[u], 0.0f);
            }
        } else if (e < 32) {
            int e2 = e - 2;
            int L = e2 / 10, rem = e2 % 10;
            int tau = rem / 5, b = rem % 5;
            int u = 32 * tau + m;
            if (b < 4) {
                int k0 = 16 * b + 4 * h;
                const float* Wp = Whid + L * 4096 + u;
                w0 = pkbf(Wp[(k0 + 0)  * 64], Wp[(k0 + 1)  * 64]);
                w1 = pkbf(Wp[(k0 + 2)  * 64], Wp[(k0 + 3)  * 64]);
                w2 = pkbf(Wp[(k0 + 8)  * 64], Wp[(k0 + 9)  * 64]);
                w3 = pkbf(Wp[(k0 + 10) * 64], Wp[(k0 + 11) * 64]);
            } else {
                if (h == 0) w0 = pkbf(bhid[L * 64 + u], 0.0f);
            }
        } else {
            int b = e - 32;
            if (m == 0) {
                int k0 = 16 * b + 4 * h;
                w0 = pkbf(Wout[k0 + 0],  Wout[k0 + 1]);
                w1 = pkbf(Wout[k0 + 2],  Wout[k0 + 3]);
                w2 = pkbf(Wout[k0 + 8],  Wout[k0 + 9]);
                w3 = pkbf(Wout[k0 + 10], Wout[k0 + 11]);
            }
        }
        fragLDS[e * 64 + l] = make_uint4(w0, w1, w2, w3);
    }
}

__device__ __forceinline__ void trans_tan(
    const f32x16& Cf0, const f32x16& Cf1, const f32x16& Ct0, const f32x16& Ct1,
    s16x8* Bf, s16x8* Bt)
{
    float sf0[16], sf1[16], st0[16], st1[16];
#pragma unroll
    for (int r = 0; r < 16; ++r) {
        float s, c;
        __sincosf(Cf0[r], &s, &c); sf0[r] = s; st0[r] = c * Ct0[r];
    }
#pragma unroll
    for (int r = 0; r < 16; ++r) {
        float s, c;
        __sincosf(Cf1[r], &s, &c); sf1[r] = s; st1[r] = c * Ct1[r];
    }
#pragma unroll
    for (int b = 0; b < 4; ++b) {
        const float* F = (b & 2) ? sf1 : sf0;
        const float* T = (b & 2) ? st1 : st0;
        unsigned wf[4], wt[4];
#pragma unroll
        for (int j = 0; j < 4; ++j) {
            const int rb = 2 * (j & 1) + 4 * (j >> 1) + 8 * (b & 1);
            wf[j] = pkbf(F[rb], F[rb + 1]);
            wt[j] = pkbf(T[rb], T[rb + 1]);
        }
        Bf[b] = frag4(wf[0], wf[1], wf[2], wf[3]);
        Bt[b] = frag4(wt[0], wt[1], wt[2], wt[3]);
    }
}

#define NTILES 1632
#define P2GRID 408

extern "C" __global__ void __launch_bounds__(256, 2)
fbsnn_phase2(const float* __restrict__ Y_Win, const float* __restrict__ Y_bin,
             const float* __restrict__ Y_Whid, const float* __restrict__ Y_bhid,
             const float* __restrict__ Y_Wout, const float* __restrict__ Y_bout,
             const float* __restrict__ y_ws, float* __restrict__ Y_ws,
             float* __restrict__ dY_ws)
{
    __shared__ uint4 fragLDS[36 * 64];

    const int tid = (int)threadIdx.x;
    const int wv  = tid >> 6;
    const int l   = tid & 63;
    const int h   = l >> 5;
    const int m   = l & 31;

    build_frags(Y_Win, Y_bin, Y_Whid, Y_bhid, Y_Wout, fragLDS, l, h, m, wv, 4);
    __syncthreads();

    const float bout = Y_bout[0];
    const s16x8 Btn  = frag4(h ? 0u : pkbf(0.0f, 1.0f), 0u, 0u, 0u);
    const s16x8 Bone = frag4(h ? 0u : pkbf(1.0f, 0.0f), 0u, 0u, 0u);

    for (int tile = (int)blockIdx.x; tile < NTILES; tile += P2GRID) {
        const int point = tile * 128 + wv * 32 + m;
        const int n = point >> 12;
        const float t = n * DT_F;
        const float y = y_ws[point];

        const s16x8 Bty = frag4(h ? 0u : pkbf(t, y), h ? 0u : pkbf(1.0f, 0.0f), 0u, 0u);

        f32x16 Cf0 = zf(), Cf1 = zf(), Ct0 = zf(), Ct1 = zf();
        {
            s16x8 A0 = frag_of(fragLDS[0 * 64 + l]);
            s16x8 A1 = frag_of(fragLDS[1 * 64 + l]);
            Cf0 = __builtin_amdgcn_mfma_f32_32x32x16_bf16(A0, Bty, Cf0, 0, 0, 0);
            Cf1 = __builtin_amdgcn_mfma_f32_32x32x16_bf16(A1, Bty, Cf1, 0, 0, 0);
            Ct0 = __builtin_amdgcn_mfma_f32_32x32x16_bf16(A0, Btn, Ct0, 0, 0, 0);
            Ct1 = __builtin_amdgcn_mfma_f32_32x32x16_bf16(A1, Btn, Ct1, 0, 0, 0);
        }
        s16x8 Bf[4], Bt[4];
        trans_tan(Cf0, Cf1, Ct0, Ct1, Bf, Bt);

#pragma unroll
        for (int L = 0; L < 3; ++L) {
            const int base = 2 + L * 10;
            Cf0 = zf(); Cf1 = zf(); Ct0 = zf(); Ct1 = zf();
            Cf0 = __builtin_amdgcn_mfma_f32_32x32x16_bf16(frag_of(fragLDS[(base + 4) * 64 + l]), Bone, Cf0, 0, 0, 0);
            Cf1 = __builtin_amdgcn_mfma_f32_32x32x16_bf16(frag_of(fragLDS[(base + 9) * 64 + l]), Bone, Cf1, 0, 0, 0);
#pragma unroll
            for (int b = 0; b < 4; ++b) {
                s16x8 A0 = frag_of(fragLDS[(base + 0 + b) * 64 + l]);
                s16x8 A1 = frag_of(fragLDS[(base + 5 + b) * 64 + l]);
                Cf0 = __builtin_amdgcn_mfma_f32_32x32x16_bf16(A0, Bf[b], Cf0, 0, 0, 0);
                Ct0 = __builtin_amdgcn_mfma_f32_32x32x16_bf16(A0, Bt[b], Ct0, 0, 0, 0);
                Cf1 = __builtin_amdgcn_mfma_f32_32x32x16_bf16(A1, Bf[b], Cf1, 0, 0, 0);
                Ct1 = __builtin_amdgcn_mfma_f32_32x32x16_bf16(A1, Bt[b], Ct1, 0, 0, 0);
            }
            trans_tan(Cf0, Cf1, Ct0, Ct1, Bf, Bt);
        }

        f32x16 Cof = zf(), Cot = zf();
#pragma unroll
        for (int b = 0; b < 4; ++b) {
            s16x8 Ao = frag_of(fragLDS[(32 + b) * 64 + l]);
            Cof = __builtin_amdgcn_mfma_f32_32x32x16_bf16(Ao, Bf[b], Cof, 0, 0, 0);
            Cot = __builtin_amdgcn_mfma_f32_32x32x16_bf16(Ao, Bt[b], Cot, 0, 0, 0);
        }
        if (h == 0) {
            Y_ws[point]  = Cof[0] + bout;
            dY_ws[point] = Cot[0];
        }
    }
}

// ================= Phase 3: residuals + reduction =================

extern "C" __global__ void __launch_bounds__(256)
fbsnn_phase3(const float* __restrict__ y_ws, const float* __restrict__ q_ws,
             const float* __restrict__ Y_ws, const float* __restrict__ dY_ws,
             const float* __restrict__ dW, float* __restrict__ out)
{
    const int p  = blockIdx.x * 256 + threadIdx.x;
    const int n0 = blockIdx.y * 10;

    float acc = 0.0f;
    float Yc  = Y_ws[n0 * NPATH + p];
#pragma unroll
    for (int k = 0; k < 10; ++k) {
        const int n = n0 + k;
        float q    = q_ws[n * NPATH + p];
        float dYc  = dY_ws[n * NPATH + p];
        float dws  = dW[n * NPATH + p] * SQRT_DT;
        float Yn   = Y_ws[(n + 1) * NPATH + p];
        float Ytil = fmaf(-q * q, DT_F, Yc) + (SIGMA_F * dYc) * dws;
        float r    = Yn - Ytil;
        acc = fmaf(r, r, acc);
        Yc = Yn;
    }
    if (blockIdx.y == 4) {
        float y50  = y_ws[NSTEP * NPATH + p];
        float dY50 = dY_ws[NSTEP * NPATH + p];
        float r1 = Yc - y50 * y50;
        float r2 = dY50 - 2.0f * y50;
        acc = fmaf(r1, r1, fmaf(r2, r2, acc));
    }

    float v = acc;
#pragma unroll
    for (int off = 32; off > 0; off >>= 1) v += __shfl_down(v, off, 64);
    if ((threadIdx.x & 63) == 0) atomicAdd(out, v * (1.0f / (float)NPATH));
}

// ================= host launch =================

extern "C" void kernel_launch(void* const* d_in, const int* in_sizes, int n_in,
                              void* d_out, int out_size, void* d_ws, size_t ws_size,
                              hipStream_t stream)
{
    const float* Y_Win  = (const float*)d_in[0];
    const float* Y_bin  = (const float*)d_in[1];
    const float* Y_Whid = (const float*)d_in[2];
    const float* Y_bhid = (const float*)d_in[3];
    const float* Y_Wout = (const float*)d_in[4];
    const float* Y_bout = (const float*)d_in[5];
    const float* q_Win  = (const float*)d_in[6];
    const float* q_bin  = (const float*)d_in[7];
    const float* q_Whid = (const float*)d_in[8];
    const float* q_bhid = (const float*)d_in[9];
    const float* q_Wout = (const float*)d_in[10];
    const float* q_bout = (const float*)d_in[11];
    const float* y0p    = (const float*)d_in[12];
    const float* dW     = (const float*)d_in[13];

    float* ws    = (float*)d_ws;
    float* y_ws  = ws;                          // 51*4096
    float* q_ws  = ws + 51 * NPATH;             // 50*4096
    float* Y_ws  = ws + 101 * NPATH;            // 51*4096
    float* dY_ws = ws + 152 * NPATH;            // 51*4096

    hipMemsetAsync(d_out, 0, sizeof(float), stream);

    fbsnn_phase1<<<dim3(256), dim3(64), 0, stream>>>(
        q_Win, q_bin, q_Whid, q_bhid, q_Wout, q_bout, y0p, dW, y_ws, q_ws);

    fbsnn_phase2<<<dim3(P2GRID), dim3(256), 0, stream>>>(
        Y_Win, Y_bin, Y_Whid, Y_bhid, Y_Wout, Y_bout, y_ws, Y_ws, dY_ws);

    fbsnn_phase3<<<dim3(NPATH / 256, 5), dim3(256), 0, stream>>>(
        y_ws, q_ws, Y_ws, dY_ws, dW, (float*)d_out);
}